// Round 13
// baseline (1723.329 us; speedup 1.0000x reference)
//
#include <hip/hip_runtime.h>

#define NN 50000
#define NE 1600000
#define NGR 64
#define XD 32
#define HID 128
#define NF 128
#define NG 50
#define GD 16
#define NL 6
#define SH 64
#define EPSF 1e-5f
#define TBL 4096          // filter table knots
#define INVSTEP 320.0f    // 1/step; covers d in [0, 12.8]

typedef __bf16 bf16_t;
typedef bf16_t bf16x8 __attribute__((ext_vector_type(8)));
typedef float f32x4 __attribute__((ext_vector_type(4)));

__device__ __forceinline__ unsigned pack_bf2(float a, float b) {
  unsigned short ua = __builtin_bit_cast(unsigned short, (bf16_t)a);
  unsigned short ub = __builtin_bit_cast(unsigned short, (bf16_t)b);
  return (unsigned)ua | ((unsigned)ub << 16);
}
__device__ __forceinline__ float bflo(unsigned u) { return __uint_as_float(u << 16); }
__device__ __forceinline__ float bfhi(unsigned u) { return __uint_as_float(u & 0xffff0000u); }
__device__ __forceinline__ float blerp(unsigned u, float fr) {
  float w0 = bflo(u), w1 = bfhi(u);
  return fmaf(fr, w1 - w0, w0);
}

// ================= CSR build (once; col constant across layers) ============
__global__ __launch_bounds__(256) void k_hist(const int* __restrict__ col,
                                              int* __restrict__ hist) {
  for (int e = blockIdx.x * 256 + threadIdx.x; e < NE; e += gridDim.x * 256)
    atomicAdd(&hist[col[e]], 1);
}

__global__ __launch_bounds__(1024) void k_scan(int* __restrict__ hist,
                                               int* __restrict__ rowptr) {
  const int tid = threadIdx.x;
  const int CH = 49;
  const int base = tid * CH;
  int s = 0;
  for (int i = 0; i < CH; ++i) {
    int idx = base + i;
    if (idx < NN) s += hist[idx];
  }
  __shared__ int part[1024];
  part[tid] = s;
  __syncthreads();
  for (int off = 1; off < 1024; off <<= 1) {
    int v = (tid >= off) ? part[tid - off] : 0;
    __syncthreads();
    part[tid] += v;
    __syncthreads();
  }
  int run = part[tid] - s;
  for (int i = 0; i < CH; ++i) {
    int idx = base + i;
    if (idx < NN) {
      int c = hist[idx];
      rowptr[idx] = run;
      hist[idx] = run;
      run += c;
    }
  }
  if (tid == 0) rowptr[NN] = NE;
}

// scatter + per-edge packed meta: metap[pos] = (row<<16 | idx<<4 | dst&15, frac)
__global__ __launch_bounds__(256) void k_scatter2(const int* __restrict__ col,
    const int* __restrict__ row, const float* __restrict__ eattr,
    int* __restrict__ cursor, uint2* __restrict__ metap) {
  for (int e = blockIdx.x * 256 + threadIdx.x; e < NE; e += gridDim.x * 256) {
    float ax = eattr[(size_t)e * 3], ay = eattr[(size_t)e * 3 + 1], az = eattr[(size_t)e * 3 + 2];
    float d = sqrtf(ax * ax + ay * ay + az * az);
    float tt = fminf(d * INVSTEP, (float)(TBL - 2) + 0.999f);
    int id = (int)tt;
    int c = col[e];
    int pos = atomicAdd(&cursor[c], 1);
    unsigned mw = ((unsigned)row[e] << 16) | ((unsigned)id << 4) | (unsigned)(c & 15);
    metap[pos] = make_uint2(mw, __float_as_uint(tt - (float)id));
  }
}

// ================= filter table build (packed bf16 pairs, direct) ==========
__global__ __launch_bounds__(128) void k_tabbuild3(
    const float* __restrict__ Wf1, const float* __restrict__ bf1,
    const float* __restrict__ Wf2, const float* __restrict__ bf2,
    unsigned int* __restrict__ tabp) {
  const int bid = blockIdx.x;            // 0 .. NL*(TBL/8)-1
  const int l = bid / (TBL / 8);
  const int t0 = (bid - l * (TBL / 8)) * 8;
  const int c = threadIdx.x;
  __shared__ float g_s[9][NG];
  __shared__ float f1_s[9][NF];
  for (int i = c; i < 9 * NG; i += 128) {
    int kk = i / NG, g = i - kk * NG;
    int t = min(t0 + kk, TBL - 1);
    float d = (float)t * (1.0f / INVSTEP);
    float z = d - 0.2040816327f * (float)g;
    g_s[kk][g] = expf(-12.005f * z * z);
  }
  __syncthreads();
  const float* W1 = Wf1 + (size_t)l * NG * NF;
  float f1r[9];
#pragma unroll
  for (int kk = 0; kk < 9; ++kk) f1r[kk] = bf1[(size_t)l * NF + c];
  for (int g = 0; g < NG; ++g) {
    float w = W1[g * NF + c];
#pragma unroll
    for (int kk = 0; kk < 9; ++kk) f1r[kk] = fmaf(g_s[kk][g], w, f1r[kk]);
  }
#pragma unroll
  for (int kk = 0; kk < 9; ++kk) f1_s[kk][c] = fmaxf(f1r[kk], 0.f);
  __syncthreads();
  const float* W2 = Wf2 + (size_t)l * NF * NF;
  float outr[9];
#pragma unroll
  for (int kk = 0; kk < 9; ++kk) outr[kk] = bf2[(size_t)l * NF + c];
  for (int k = 0; k < NF; ++k) {
    float w = W2[k * NF + c];
#pragma unroll
    for (int kk = 0; kk < 9; ++kk) outr[kk] = fmaf(f1_s[kk][k], w, outr[kk]);
  }
#pragma unroll
  for (int kk = 0; kk < 8; ++kk)
    tabp[((size_t)l * TBL + t0 + kk) * NF + c] = pack_bf2(outr[kk], outr[kk + 1]);
}

// ================= weight prep: node MLP (transpose + split hi/lo) =========
__global__ __launch_bounds__(256) void k_prepw(const float* __restrict__ Wd1,
    const float* __restrict__ Wd2,
    bf16_t* __restrict__ Wd1Thi, bf16_t* __restrict__ Wd1Tlo,
    bf16_t* __restrict__ Wd2Thi, bf16_t* __restrict__ Wd2Tlo) {
  const int S1 = NL * 128 * 128;
  int idx = blockIdx.x * 256 + threadIdx.x;
  if (idx < 2 * S1) {
    int which = idx / S1;  // 0: Wd1, 1: Wd2
    int jj = idx - which * S1;
    int l = jj / (128 * 128);
    int r = jj - l * (128 * 128);
    int c = r >> 7, k = r & 127;
    const float* W = (which == 0) ? Wd1 : Wd2;
    float v = W[(size_t)l * 128 * 128 + (size_t)k * 128 + c];
    bf16_t hv = (bf16_t)v;
    bf16_t lv = (bf16_t)(v - (float)hv);
    if (which == 0) { Wd1Thi[jj] = hv; Wd1Tlo[jj] = lv; }
    else            { Wd2Thi[jj] = hv; Wd2Tlo[jj] = lv; }
  }
}

// ================= weight prep: enc2/shift weights =========================
__global__ __launch_bounds__(256) void k_prepw2(const float* __restrict__ We2,
    const float* __restrict__ Ws1, const float* __restrict__ Ws2,
    bf16_t* __restrict__ We2Thi, bf16_t* __restrict__ We2Tlo,
    bf16_t* __restrict__ Ws1Thi, bf16_t* __restrict__ Ws1Tlo,
    bf16_t* __restrict__ Ws2Thi, bf16_t* __restrict__ Ws2Tlo) {
  const int S0 = 128 * 128;
  const int S1 = 64 * 256;
  const int S2 = 64 * 64;
  int idx = blockIdx.x * 256 + threadIdx.x;
  if (idx < S0) {
    int c = idx >> 7, k = idx & 127;
    float v = We2[k * 128 + c];
    bf16_t hv = (bf16_t)v;
    We2Thi[idx] = hv; We2Tlo[idx] = (bf16_t)(v - (float)hv);
  } else if (idx < S0 + S1) {
    int j = idx - S0;
    int c = j >> 8, k = j & 255;
    float v = Ws1[k * 64 + c];
    bf16_t hv = (bf16_t)v;
    Ws1Thi[j] = hv; Ws1Tlo[j] = (bf16_t)(v - (float)hv);
  } else if (idx < S0 + S1 + S2) {
    int j = idx - S0 - S1;
    int c = j >> 6, k = j & 63;
    float v = Ws2[k * 64 + c];
    bf16_t hv = (bf16_t)v;
    Ws2Thi[j] = hv; Ws2Tlo[j] = (bf16_t)(v - (float)hv);
  }
}

// ================= node encoder pass 1 =====================================
__global__ __launch_bounds__(256) void k_enc1(const float* __restrict__ x,
    const float* __restrict__ We1, const float* __restrict__ be1,
    float* __restrict__ t, float* __restrict__ stats) {
  int c = threadIdx.x & 127;
  int half = threadIdx.x >> 7;
  float b = be1[c];
  float psum = 0.f, psq = 0.f;
  for (int n = blockIdx.x * 2 + half; n < NN; n += gridDim.x * 2) {
    const float* xr = x + (size_t)n * XD;
    float v = b;
#pragma unroll
    for (int k = 0; k < XD; ++k) v = fmaf(xr[k], We1[k * HID + c], v);
    t[(size_t)n * HID + c] = v;
    psum += v; psq += v * v;
  }
  __shared__ float s0[256], s1[256];
  s0[threadIdx.x] = psum; s1[threadIdx.x] = psq;
  __syncthreads();
  if (threadIdx.x < 128) {
    atomicAdd(&stats[threadIdx.x], s0[threadIdx.x] + s0[threadIdx.x + 128]);
    atomicAdd(&stats[128 + threadIdx.x], s1[threadIdx.x] + s1[threadIdx.x + 128]);
  }
}

__global__ __launch_bounds__(128) void k_bn_fin(const float* __restrict__ gamma,
    const float* __restrict__ beta, float* __restrict__ stats, int C, float invn) {
  int c = threadIdx.x;
  if (c < C) {
    float mean = stats[c] * invn;
    float var = stats[128 + c] * invn - mean * mean;
    float a = gamma[c] * rsqrtf(var + EPSF);
    stats[256 + c] = a;
    stats[384 + c] = beta[c] - mean * a;
  }
}

// ================= node encoder pass 2 (MFMA) ==============================
__global__ __launch_bounds__(256) void k_enc2m(const float* __restrict__ t,
    const float* __restrict__ stats,
    const bf16_t* __restrict__ We2Thi, const bf16_t* __restrict__ We2Tlo,
    const float* __restrict__ be2, float* __restrict__ h,
    unsigned int* __restrict__ hbf) {
  __shared__ __align__(16) bf16_t rhi[16][136];
  __shared__ __align__(16) bf16_t rlo[16][136];
  const int tid = threadIdx.x, lane = tid & 63, w = tid >> 6;
  const int lm = lane & 15, lk = lane >> 4;
  const int nb = blockIdx.x * 16;
  for (int i = tid; i < 16 * 128; i += 256) {
    int r = i >> 7, k = i & 127;
    float v = fmaxf(fmaf(t[(size_t)(nb + r) * HID + k], stats[256 + k], stats[384 + k]), 0.f);
    bf16_t hv = (bf16_t)v;
    rhi[r][k] = hv; rlo[r][k] = (bf16_t)(v - (float)hv);
  }
  __syncthreads();
  const int colb = w * 32, k0base = lk * 8;
  f32x4 acc[2];
  acc[0] = (f32x4){0.f, 0.f, 0.f, 0.f};
  acc[1] = (f32x4){0.f, 0.f, 0.f, 0.f};
#pragma unroll
  for (int s = 0; s < 4; ++s) {
    int k0 = s * 32 + k0base;
    bf16x8 Ahi = *(const bf16x8*)&rhi[lm][k0];
    bf16x8 Alo = *(const bf16x8*)&rlo[lm][k0];
#pragma unroll
    for (int cf = 0; cf < 2; ++cf) {
      int cc = colb + cf * 16 + lm;
      bf16x8 Bh = *(const bf16x8*)(We2Thi + (size_t)cc * 128 + k0);
      bf16x8 Bl = *(const bf16x8*)(We2Tlo + (size_t)cc * 128 + k0);
      acc[cf] = __builtin_amdgcn_mfma_f32_16x16x32_bf16(Ahi, Bh, acc[cf], 0, 0, 0);
      acc[cf] = __builtin_amdgcn_mfma_f32_16x16x32_bf16(Ahi, Bl, acc[cf], 0, 0, 0);
      acc[cf] = __builtin_amdgcn_mfma_f32_16x16x32_bf16(Alo, Bh, acc[cf], 0, 0, 0);
    }
  }
#pragma unroll
  for (int cf = 0; cf < 2; ++cf) {
    int cc = colb + cf * 16 + lm;
    float bias = be2[cc];
#pragma unroll
    for (int j = 0; j < 4; ++j) {
      int r = nb + lk * 4 + j;
      float val = acc[cf][j] + bias;
      h[(size_t)r * HID + cc] = val;
      float o = __shfl_xor(val, 1);
      if ((lm & 1) == 0) hbf[(size_t)r * 64 + (cc >> 1)] = pack_bf2(val, o);
    }
  }
}

// ================= gaussian smearing (ea output, float2 stores) ============
__global__ __launch_bounds__(256) void k_smear(const float* __restrict__ eattr,
    float* __restrict__ ea) {
  int idx = blockIdx.x * 256 + threadIdx.x;  // over NE*25
  if (idx >= NE * (NG / 2)) return;
  int e = idx / (NG / 2);
  int g0 = (idx - e * (NG / 2)) * 2;
  float ax = eattr[(size_t)e * 3], ay = eattr[(size_t)e * 3 + 1], az = eattr[(size_t)e * 3 + 2];
  float d = sqrtf(ax * ax + ay * ay + az * az);
  float z0 = d - 0.2040816327f * (float)g0;
  float z1 = d - 0.2040816327f * (float)(g0 + 1);
  float2 v = make_float2(__expf(-12.005f * z0 * z0), __expf(-12.005f * z1 * z1));
  *(float2*)(ea + (size_t)e * NG + g0) = v;
}

// ================= fused layer kernel ======================================
__global__ __launch_bounds__(256) void k_layer(
    const uint2* __restrict__ metap, const int* __restrict__ rowptr,
    const float* __restrict__ hin, const unsigned int* __restrict__ hbf,
    const unsigned int* __restrict__ tabp,
    const bf16_t* __restrict__ Wd1Thi, const bf16_t* __restrict__ Wd1Tlo,
    const bf16_t* __restrict__ Wd2Thi, const bf16_t* __restrict__ Wd2Tlo,
    const float* __restrict__ bd1, const float* __restrict__ bd2,
    float* __restrict__ hout, unsigned int* __restrict__ hbfo) {
  __shared__ __align__(16) char up[8704];          // agg_s  ∪  (t1hi,t1lo)
  float (*agg_s)[HID] = (float(*)[HID])up;
  bf16_t (*t1hi)[136] = (bf16_t(*)[136])up;
  bf16_t (*t1lo)[136] = (bf16_t(*)[136])(up + 4352);
  __shared__ __align__(16) bf16_t ahi_s[16][136];
  __shared__ __align__(16) bf16_t alo_s[16][136];

  const int tid = threadIdx.x;
  const int lane = tid & 63;
  const int w = tid >> 6;
  const int half = lane >> 5;          // which edge of the pair
  const int c0 = (lane & 31) * 4;      // 4 owned cols
  const int hoff = c0 >> 1;            // u32 index into hbf row
  const int nb = blockIdx.x * 16;
  const int eS = rowptr[nb], eE = rowptr[nb + 16];

  for (int i = tid; i < 16 * HID; i += 256) ((float*)agg_s)[i] = 0.f;
  __syncthreads();

  // ---------------- phase 1: edges (2-deep pipelined pairs) ----------------
  {
    const int Q = (eE - eS + 3) >> 2;
    int e = eS + w * Q;
    const int wE = min(e + Q, eE);

    float a0 = 0.f, a1 = 0.f, a2 = 0.f, a3 = 0.f;
    int cur = -1;

    auto flush = [&]() {
      if (cur >= 0) {
        atomicAdd(&agg_s[cur][c0], a0);
        atomicAdd(&agg_s[cur][c0 + 1], a1);
        atomicAdd(&agg_s[cur][c0 + 2], a2);
        atomicAdd(&agg_s[cur][c0 + 3], a3);
      }
    };
    auto pbody = [&](const uint2& m, const uint2& hv, const uint4& tv) {
      float fr = __uint_as_float(m.y);
      int dst = m.x & 0xF;
      float m0 = blerp(tv.x, fr) * bflo(hv.x);
      float m1 = blerp(tv.y, fr) * bfhi(hv.x);
      float m2 = blerp(tv.z, fr) * bflo(hv.y);
      float m3 = blerp(tv.w, fr) * bfhi(hv.y);
      if (dst != cur) {
        flush();
        cur = dst; a0 = m0; a1 = m1; a2 = m2; a3 = m3;
      } else {
        a0 += m0; a1 += m1; a2 += m2; a3 += m3;
      }
    };
    auto loadd = [&](const uint2& m, uint2& hv, uint4& tv) {
      hv = *(const uint2*)(hbf + (size_t)(m.x >> 16) * 64 + hoff);
      tv = *(const uint4*)(tabp + (size_t)((m.x >> 4) & 0xFFFu) * HID + c0);
    };

    if (wE - e >= 8) {
      uint2 m0a = metap[e + half], m0b = metap[e + 2 + half];
      uint2 hv0a, hv0b; uint4 tv0a, tv0b;
      loadd(m0a, hv0a, tv0a); loadd(m0b, hv0b, tv0b);
      int ep = e + 4;
      uint2 m1a = metap[ep + half], m1b = metap[ep + 2 + half];
      while (true) {
        const bool more = (ep + 8 <= wE);
        uint2 hv1a, hv1b; uint4 tv1a, tv1b;
        loadd(m1a, hv1a, tv1a); loadd(m1b, hv1b, tv1b);
        uint2 m2a, m2b;
        if (more) { m2a = metap[ep + 4 + half]; m2b = metap[ep + 6 + half]; }
        pbody(m0a, hv0a, tv0a);
        pbody(m0b, hv0b, tv0b);
        if (!more) {
          pbody(m1a, hv1a, tv1a);
          pbody(m1b, hv1b, tv1b);
          ep += 4;
          break;
        }
        m0a = m1a; m0b = m1b;
        hv0a = hv1a; hv0b = hv1b; tv0a = tv1a; tv0b = tv1b;
        m1a = m2a; m1b = m2b;
        ep += 4;
      }
      e = ep;
    }
    for (; e < wE; e += 2) {
      int le = e + half;
      bool valid = le < wE;
      uint2 m = metap[valid ? le : (wE - 1)];
      uint2 hv; uint4 tv;
      loadd(m, hv, tv);
      if (valid) pbody(m, hv, tv);
    }
    flush();
  }
  __syncthreads();

  // ---------------- phase 2: node MLP on agg_s ----------------
  for (int i = tid; i < 16 * 128; i += 256) {
    int r = i >> 7, k = i & 127;
    float v = agg_s[r][k];
    bf16_t hv = (bf16_t)v;
    ahi_s[r][k] = hv;
    alo_s[r][k] = (bf16_t)(v - (float)hv);
  }
  __syncthreads();  // agg_s dead; t1hi/t1lo may now overwrite it

  const int lm = lane & 15;
  const int lk = lane >> 4;
  const int colb = w * 32;
  const int k0base = lk * 8;

  // GEMM1: t1 = relu(agg @ Wd1 + bd1)
  f32x4 acc1g[2];
  acc1g[0] = (f32x4){0.f, 0.f, 0.f, 0.f};
  acc1g[1] = (f32x4){0.f, 0.f, 0.f, 0.f};
#pragma unroll
  for (int s = 0; s < 4; ++s) {
    int k0 = s * 32 + k0base;
    bf16x8 Ahi = *(const bf16x8*)&ahi_s[lm][k0];
    bf16x8 Alo = *(const bf16x8*)&alo_s[lm][k0];
#pragma unroll
    for (int cf = 0; cf < 2; ++cf) {
      int cc = colb + cf * 16 + lm;
      bf16x8 Bh = *(const bf16x8*)(Wd1Thi + (size_t)cc * 128 + k0);
      bf16x8 Bl = *(const bf16x8*)(Wd1Tlo + (size_t)cc * 128 + k0);
      acc1g[cf] = __builtin_amdgcn_mfma_f32_16x16x32_bf16(Ahi, Bh, acc1g[cf], 0, 0, 0);
      acc1g[cf] = __builtin_amdgcn_mfma_f32_16x16x32_bf16(Ahi, Bl, acc1g[cf], 0, 0, 0);
      acc1g[cf] = __builtin_amdgcn_mfma_f32_16x16x32_bf16(Alo, Bh, acc1g[cf], 0, 0, 0);
    }
  }
#pragma unroll
  for (int cf = 0; cf < 2; ++cf) {
    int cc = colb + cf * 16 + lm;
    float bias1 = bd1[cc];
#pragma unroll
    for (int j = 0; j < 4; ++j) {
      int r = lk * 4 + j;
      float v = fmaxf(acc1g[cf][j] + bias1, 0.f);
      bf16_t hv = (bf16_t)v;
      t1hi[r][cc] = hv;
      t1lo[r][cc] = (bf16_t)(v - (float)hv);
    }
  }
  __syncthreads();

  // GEMM2: out = t1 @ Wd2 + bd2;  hout = hin + out (+ packed bf16 copy)
  f32x4 acc2g[2];
  acc2g[0] = (f32x4){0.f, 0.f, 0.f, 0.f};
  acc2g[1] = (f32x4){0.f, 0.f, 0.f, 0.f};
#pragma unroll
  for (int s = 0; s < 4; ++s) {
    int k0 = s * 32 + k0base;
    bf16x8 Ahi = *(const bf16x8*)&t1hi[lm][k0];
    bf16x8 Alo = *(const bf16x8*)&t1lo[lm][k0];
#pragma unroll
    for (int cf = 0; cf < 2; ++cf) {
      int cc = colb + cf * 16 + lm;
      bf16x8 Bh = *(const bf16x8*)(Wd2Thi + (size_t)cc * 128 + k0);
      bf16x8 Bl = *(const bf16x8*)(Wd2Tlo + (size_t)cc * 128 + k0);
      acc2g[cf] = __builtin_amdgcn_mfma_f32_16x16x32_bf16(Ahi, Bh, acc2g[cf], 0, 0, 0);
      acc2g[cf] = __builtin_amdgcn_mfma_f32_16x16x32_bf16(Ahi, Bl, acc2g[cf], 0, 0, 0);
      acc2g[cf] = __builtin_amdgcn_mfma_f32_16x16x32_bf16(Alo, Bh, acc2g[cf], 0, 0, 0);
    }
  }
#pragma unroll
  for (int cf = 0; cf < 2; ++cf) {
    int cc = colb + cf * 16 + lm;
    float bias2 = bd2[cc];
#pragma unroll
    for (int j = 0; j < 4; ++j) {
      int r = nb + lk * 4 + j;
      float val = hin[(size_t)r * HID + cc] + acc2g[cf][j] + bias2;
      hout[(size_t)r * HID + cc] = val;
      float o = __shfl_xor(val, 1);
      if ((lm & 1) == 0) hbfo[(size_t)r * 64 + (cc >> 1)] = pack_bf2(val, o);
    }
  }
}

// ================= global MLP ==============================================
__global__ __launch_bounds__(128) void k_global(const float* __restrict__ u,
    const float* __restrict__ Wg1, const float* __restrict__ bg1,
    const float* __restrict__ gg1, const float* __restrict__ btg1,
    const float* __restrict__ Wg2, const float* __restrict__ bg2,
    float* __restrict__ u_p) {
  __shared__ float t_s[NGR][HID];
  int c = threadIdx.x;
  for (int g = 0; g < NGR; ++g) {
    float v = bg1[c];
#pragma unroll
    for (int k = 0; k < GD; ++k) v = fmaf(u[(size_t)g * GD + k], Wg1[k * HID + c], v);
    t_s[g][c] = v;
  }
  float sum = 0.f, sq = 0.f;
  for (int g = 0; g < NGR; ++g) { float v = t_s[g][c]; sum += v; sq += v * v; }
  float mean = sum * (1.f / NGR);
  float var = sq * (1.f / NGR) - mean * mean;
  float a = gg1[c] * rsqrtf(var + EPSF);
  float b = btg1[c] - mean * a;
  for (int g = 0; g < NGR; ++g) t_s[g][c] = fmaxf(fmaf(t_s[g][c], a, b), 0.f);
  __syncthreads();
  for (int g = 0; g < NGR; ++g) {
    float acc = bg2[c];
#pragma unroll 8
    for (int k = 0; k < HID; ++k) acc = fmaf(t_s[g][k], Wg2[k * HID + c], acc);
    u_p[(size_t)g * HID + c] = acc;
  }
}

// ================= shift head pass 1 (MFMA, K=256) =========================
__global__ __launch_bounds__(256) void k_shift1m(
    const float* __restrict__ h, const float* __restrict__ u_p,
    const int* __restrict__ batch,
    const bf16_t* __restrict__ Ws1Thi, const bf16_t* __restrict__ Ws1Tlo,
    const float* __restrict__ bs1, float* __restrict__ t1,
    float* __restrict__ stats) {
  __shared__ __align__(16) bf16_t shi[16][264];
  __shared__ __align__(16) bf16_t slo[16][264];
  const int tid = threadIdx.x, lane = tid & 63, w = tid >> 6;
  const int lm = lane & 15, lk = lane >> 4;
  const int nb = blockIdx.x * 16;
  for (int i = tid; i < 16 * 128; i += 256) {
    int ln = i >> 7, k = i & 127;
    float v1 = h[(size_t)(nb + ln) * HID + k];
    float v2 = u_p[(size_t)batch[nb + ln] * HID + k];
    bf16_t h1 = (bf16_t)v1;
    shi[ln][k] = h1; slo[ln][k] = (bf16_t)(v1 - (float)h1);
    bf16_t h2 = (bf16_t)v2;
    shi[ln][128 + k] = h2; slo[ln][128 + k] = (bf16_t)(v2 - (float)h2);
  }
  __syncthreads();
  const int cc = w * 16 + lm;
  f32x4 acc = (f32x4){0.f, 0.f, 0.f, 0.f};
#pragma unroll
  for (int s = 0; s < 8; ++s) {
    int k0 = s * 32 + lk * 8;
    bf16x8 Ahi = *(const bf16x8*)&shi[lm][k0];
    bf16x8 Alo = *(const bf16x8*)&slo[lm][k0];
    bf16x8 Bh = *(const bf16x8*)(Ws1Thi + (size_t)cc * 256 + k0);
    bf16x8 Bl = *(const bf16x8*)(Ws1Tlo + (size_t)cc * 256 + k0);
    acc = __builtin_amdgcn_mfma_f32_16x16x32_bf16(Ahi, Bh, acc, 0, 0, 0);
    acc = __builtin_amdgcn_mfma_f32_16x16x32_bf16(Ahi, Bl, acc, 0, 0, 0);
    acc = __builtin_amdgcn_mfma_f32_16x16x32_bf16(Alo, Bh, acc, 0, 0, 0);
  }
  float bias = bs1[cc];
  float psum = 0.f, psq = 0.f;
#pragma unroll
  for (int j = 0; j < 4; ++j) {
    float val = acc[j] + bias;
    t1[(size_t)(nb + lk * 4 + j) * SH + cc] = val;
    psum += val; psq += val * val;
  }
  psum += __shfl_xor(psum, 16); psum += __shfl_xor(psum, 32);
  psq  += __shfl_xor(psq, 16);  psq  += __shfl_xor(psq, 32);
  if (lk == 0) {
    atomicAdd(&stats[cc], psum);
    atomicAdd(&stats[128 + cc], psq);
  }
}

// ================= shift head pass 2 (MFMA, K=64) ==========================
__global__ __launch_bounds__(256) void k_shift2m(
    const float* __restrict__ t1, float* __restrict__ stats,
    const bf16_t* __restrict__ Ws2Thi, const bf16_t* __restrict__ Ws2Tlo,
    const float* __restrict__ bs2, float* __restrict__ t2) {
  __shared__ __align__(16) bf16_t rhi[16][72];
  __shared__ __align__(16) bf16_t rlo[16][72];
  const int tid = threadIdx.x, lane = tid & 63, w = tid >> 6;
  const int lm = lane & 15, lk = lane >> 4;
  const int nb = blockIdx.x * 16;
  for (int i = tid; i < 16 * 64; i += 256) {
    int ln = i >> 6, k = i & 63;
    float v = fmaxf(fmaf(t1[(size_t)(nb + ln) * SH + k], stats[256 + k], stats[384 + k]), 0.f);
    bf16_t hv = (bf16_t)v;
    rhi[ln][k] = hv; rlo[ln][k] = (bf16_t)(v - (float)hv);
  }
  __syncthreads();
  const int cc = w * 16 + lm;
  f32x4 acc = (f32x4){0.f, 0.f, 0.f, 0.f};
#pragma unroll
  for (int s = 0; s < 2; ++s) {
    int k0 = s * 32 + lk * 8;
    bf16x8 Ahi = *(const bf16x8*)&rhi[lm][k0];
    bf16x8 Alo = *(const bf16x8*)&rlo[lm][k0];
    bf16x8 Bh = *(const bf16x8*)(Ws2Thi + (size_t)cc * 64 + k0);
    bf16x8 Bl = *(const bf16x8*)(Ws2Tlo + (size_t)cc * 64 + k0);
    acc = __builtin_amdgcn_mfma_f32_16x16x32_bf16(Ahi, Bh, acc, 0, 0, 0);
    acc = __builtin_amdgcn_mfma_f32_16x16x32_bf16(Ahi, Bl, acc, 0, 0, 0);
    acc = __builtin_amdgcn_mfma_f32_16x16x32_bf16(Alo, Bh, acc, 0, 0, 0);
  }
  float bias = bs2[cc];
  float psum = 0.f, psq = 0.f;
#pragma unroll
  for (int j = 0; j < 4; ++j) {
    float val = acc[j] + bias;
    t2[(size_t)(nb + lk * 4 + j) * SH + cc] = val;
    psum += val; psq += val * val;
  }
  psum += __shfl_xor(psum, 16); psum += __shfl_xor(psum, 32);
  psq  += __shfl_xor(psq, 16);  psq  += __shfl_xor(psq, 32);
  if (lk == 0) {
    atomicAdd(&stats[cc], psum);
    atomicAdd(&stats[128 + cc], psq);
  }
}

__global__ __launch_bounds__(256) void k_shift3(
    const float* __restrict__ t2, const float* __restrict__ stats,
    const float* __restrict__ Ws3, const float* __restrict__ bs3,
    float* __restrict__ shifts) {
  int lane = threadIdx.x & 63;
  int n = blockIdx.x * 4 + (threadIdx.x >> 6);
  if (n >= NN) return;
  float a = stats[256 + lane], b = stats[384 + lane];
  float r = fmaxf(fmaf(t2[(size_t)n * SH + lane], a, b), 0.f);
  float v = r * Ws3[lane];
#pragma unroll
  for (int off = 32; off; off >>= 1) v += __shfl_down(v, off);
  if (lane == 0) shifts[n] = v + bs3[0];
}

extern "C" void kernel_launch(void* const* d_in, const int* in_sizes, int n_in,
                              void* d_out, int out_size, void* d_ws, size_t ws_size,
                              hipStream_t stream) {
  const float* x     = (const float*)d_in[0];
  const int*   ei    = (const int*)d_in[1];
  const float* eattr = (const float*)d_in[2];
  const int*   batch = (const int*)d_in[3];
  const float* u     = (const float*)d_in[4];
  const float* We1 = (const float*)d_in[5];  const float* be1 = (const float*)d_in[6];
  const float* ge1 = (const float*)d_in[7];  const float* bte1 = (const float*)d_in[8];
  const float* We2 = (const float*)d_in[9];  const float* be2 = (const float*)d_in[10];
  const float* Wf1 = (const float*)d_in[11]; const float* bf1 = (const float*)d_in[12];
  const float* Wf2 = (const float*)d_in[13]; const float* bf2 = (const float*)d_in[14];
  const float* Wd1 = (const float*)d_in[15]; const float* bd1 = (const float*)d_in[16];
  const float* Wd2 = (const float*)d_in[17]; const float* bd2 = (const float*)d_in[18];
  const float* Wg1 = (const float*)d_in[19]; const float* bg1 = (const float*)d_in[20];
  const float* gg1 = (const float*)d_in[21]; const float* btg1 = (const float*)d_in[22];
  const float* Wg2 = (const float*)d_in[23]; const float* bg2 = (const float*)d_in[24];
  const float* Ws1 = (const float*)d_in[25]; const float* bs1 = (const float*)d_in[26];
  const float* gs1 = (const float*)d_in[27]; const float* bts1 = (const float*)d_in[28];
  const float* Ws2 = (const float*)d_in[29]; const float* bs2 = (const float*)d_in[30];
  const float* gs2 = (const float*)d_in[31]; const float* bts2 = (const float*)d_in[32];
  const float* Ws3 = (const float*)d_in[33]; const float* bs3 = (const float*)d_in[34];

  float* out    = (float*)d_out;
  float* shifts = out;                    // [NN]
  float* h      = out + NN;               // [NN,HID]
  float* ea     = out + NN + NN * HID;    // [NE,NG]
  float* u_p    = out + NN + NN * HID + (size_t)NE * NG;  // [NGR,HID]

  // workspace layout
  char* wsb = (char*)d_ws;
  size_t off = 0;
  auto alloc = [&](size_t bytes) { void* p = wsb + off; off = (off + bytes + 255) & ~(size_t)255; return p; };
  float*  stats    = (float*)alloc(512 * sizeof(float));
  int*    hist     = (int*)alloc((size_t)NN * sizeof(int));
  int*    rowptr   = (int*)alloc((size_t)(NN + 1) * sizeof(int));
  uint2*  metap    = (uint2*)alloc((size_t)NE * sizeof(uint2));
  unsigned int* tabp = (unsigned int*)alloc((size_t)NL * TBL * HID * sizeof(unsigned int));
  bf16_t* Wd1Thi   = (bf16_t*)alloc((size_t)NL * 128 * 128 * sizeof(bf16_t));
  bf16_t* Wd1Tlo   = (bf16_t*)alloc((size_t)NL * 128 * 128 * sizeof(bf16_t));
  bf16_t* Wd2Thi   = (bf16_t*)alloc((size_t)NL * 128 * 128 * sizeof(bf16_t));
  bf16_t* Wd2Tlo   = (bf16_t*)alloc((size_t)NL * 128 * 128 * sizeof(bf16_t));
  bf16_t* We2Thi   = (bf16_t*)alloc((size_t)128 * 128 * sizeof(bf16_t));
  bf16_t* We2Tlo   = (bf16_t*)alloc((size_t)128 * 128 * sizeof(bf16_t));
  bf16_t* Ws1Thi   = (bf16_t*)alloc((size_t)64 * 256 * sizeof(bf16_t));
  bf16_t* Ws1Tlo   = (bf16_t*)alloc((size_t)64 * 256 * sizeof(bf16_t));
  bf16_t* Ws2Thi   = (bf16_t*)alloc((size_t)64 * 64 * sizeof(bf16_t));
  bf16_t* Ws2Tlo   = (bf16_t*)alloc((size_t)64 * 64 * sizeof(bf16_t));
  float*  hwork    = (float*)alloc((size_t)NN * HID * sizeof(float));
  unsigned int* hbfA = (unsigned int*)alloc((size_t)NN * 64 * sizeof(unsigned int));
  unsigned int* hbfB = (unsigned int*)alloc((size_t)NN * 64 * sizeof(unsigned int));
  float*  buf1     = (float*)alloc((size_t)NN * HID * sizeof(float));
  float* t1 = buf1;
  float* t2 = buf1 + (size_t)NN * SH;

  const int* row = ei;        // source j
  const int* col = ei + NE;   // target i

  // ---- CSR build + packed edge meta + table + weight prep
  hipMemsetAsync(hist, 0, (size_t)NN * sizeof(int), stream);
  k_hist<<<512, 256, 0, stream>>>(col, hist);
  k_scan<<<1, 1024, 0, stream>>>(hist, rowptr);
  k_scatter2<<<512, 256, 0, stream>>>(col, row, eattr, hist, metap);
  k_tabbuild3<<<NL * (TBL / 8), 128, 0, stream>>>(Wf1, bf1, Wf2, bf2, tabp);
  k_prepw<<<(2 * NL * 128 * 128 + 255) / 256, 256, 0, stream>>>(
      Wd1, Wd2, Wd1Thi, Wd1Tlo, Wd2Thi, Wd2Tlo);
  k_prepw2<<<(128 * 128 + 64 * 256 + 64 * 64 + 255) / 256, 256, 0, stream>>>(
      We2, Ws1, Ws2, We2Thi, We2Tlo, Ws1Thi, Ws1Tlo, Ws2Thi, Ws2Tlo);

  // ---- node encoder
  hipMemsetAsync(stats, 0, 256 * sizeof(float), stream);
  k_enc1<<<512, 256, 0, stream>>>(x, We1, be1, buf1, stats);
  k_bn_fin<<<1, 128, 0, stream>>>(ge1, bte1, stats, 128, 1.f / NN);
  k_enc2m<<<NN / 16, 256, 0, stream>>>(buf1, stats, We2Thi, We2Tlo, be2, h, hbfA);

  // ---- gaussian smearing (ea output)
  k_smear<<<(NE * (NG / 2) + 255) / 256, 256, 0, stream>>>(eattr, ea);

  // ---- interaction layers (fused edge+node, ping-pong h and hbf)
  for (int l = 0; l < NL; ++l) {
    const float* hi = (l & 1) ? hwork : h;
    float*       ho = (l & 1) ? h : hwork;
    const unsigned int* bi = (l & 1) ? hbfB : hbfA;
    unsigned int*       bo = (l & 1) ? hbfA : hbfB;
    k_layer<<<NN / 16, 256, 0, stream>>>(
        metap, rowptr, hi, bi, tabp + (size_t)l * TBL * HID,
        Wd1Thi + (size_t)l * 128 * 128, Wd1Tlo + (size_t)l * 128 * 128,
        Wd2Thi + (size_t)l * 128 * 128, Wd2Tlo + (size_t)l * 128 * 128,
        bd1 + (size_t)l * HID, bd2 + (size_t)l * HID, ho, bo);
  }
  // NL=6 (even) -> final h lands back in the output slot `h`

  // ---- global MLP
  k_global<<<1, 128, 0, stream>>>(u, Wg1, bg1, gg1, btg1, Wg2, bg2, u_p);

  // ---- shift head
  hipMemsetAsync(stats, 0, 256 * sizeof(float), stream);
  k_shift1m<<<NN / 16, 256, 0, stream>>>(h, u_p, batch, Ws1Thi, Ws1Tlo, bs1, t1, stats);
  k_bn_fin<<<1, 128, 0, stream>>>(gs1, bts1, stats, 64, 1.f / NN);
  hipMemsetAsync(stats, 0, 256 * sizeof(float), stream);
  k_shift2m<<<NN / 16, 256, 0, stream>>>(t1, stats, Ws2Thi, Ws2Tlo, bs2, t2);
  k_bn_fin<<<1, 128, 0, stream>>>(gs2, bts2, stats, 64, 1.f / NN);
  k_shift3<<<(NN + 3) / 4, 256, 0, stream>>>(t2, stats, Ws3, bs3, shifts);
}

// Round 14
// 1703.565 us; speedup vs baseline: 1.0116x; 1.0116x over previous
//
#include <hip/hip_runtime.h>

#define NN 50000
#define NE 1600000
#define NGR 64
#define XD 32
#define HID 128
#define NF 128
#define NG 50
#define GD 16
#define NL 6
#define SH 64
#define EPSF 1e-5f
#define TBL 2048          // filter table knots (1 MB/layer packed -> L2-resident)
#define INVSTEP 160.0f    // 1/step; covers d in [0, 12.8]

typedef __bf16 bf16_t;
typedef bf16_t bf16x8 __attribute__((ext_vector_type(8)));
typedef float f32x4 __attribute__((ext_vector_type(4)));

__device__ __forceinline__ unsigned pack_bf2(float a, float b) {
  unsigned short ua = __builtin_bit_cast(unsigned short, (bf16_t)a);
  unsigned short ub = __builtin_bit_cast(unsigned short, (bf16_t)b);
  return (unsigned)ua | ((unsigned)ub << 16);
}
__device__ __forceinline__ float bflo(unsigned u) { return __uint_as_float(u << 16); }
__device__ __forceinline__ float bfhi(unsigned u) { return __uint_as_float(u & 0xffff0000u); }
__device__ __forceinline__ float blerp(unsigned u, float fr) {
  float w0 = bflo(u), w1 = bfhi(u);
  return fmaf(fr, w1 - w0, w0);
}

// ================= CSR build (once; col constant across layers) ============
__global__ __launch_bounds__(256) void k_hist(const int* __restrict__ col,
                                              int* __restrict__ hist) {
  for (int e = blockIdx.x * 256 + threadIdx.x; e < NE; e += gridDim.x * 256)
    atomicAdd(&hist[col[e]], 1);
}

__global__ __launch_bounds__(1024) void k_scan(int* __restrict__ hist,
                                               int* __restrict__ rowptr) {
  const int tid = threadIdx.x;
  const int CH = 49;
  const int base = tid * CH;
  int s = 0;
  for (int i = 0; i < CH; ++i) {
    int idx = base + i;
    if (idx < NN) s += hist[idx];
  }
  __shared__ int part[1024];
  part[tid] = s;
  __syncthreads();
  for (int off = 1; off < 1024; off <<= 1) {
    int v = (tid >= off) ? part[tid - off] : 0;
    __syncthreads();
    part[tid] += v;
    __syncthreads();
  }
  int run = part[tid] - s;
  for (int i = 0; i < CH; ++i) {
    int idx = base + i;
    if (idx < NN) {
      int c = hist[idx];
      rowptr[idx] = run;
      hist[idx] = run;
      run += c;
    }
  }
  if (tid == 0) rowptr[NN] = NE;
}

// scatter + per-edge packed meta: metap[pos] = (row<<16 | idx<<4 | dst&15, frac)
__global__ __launch_bounds__(256) void k_scatter2(const int* __restrict__ col,
    const int* __restrict__ row, const float* __restrict__ eattr,
    int* __restrict__ cursor, uint2* __restrict__ metap) {
  for (int e = blockIdx.x * 256 + threadIdx.x; e < NE; e += gridDim.x * 256) {
    float ax = eattr[(size_t)e * 3], ay = eattr[(size_t)e * 3 + 1], az = eattr[(size_t)e * 3 + 2];
    float d = sqrtf(ax * ax + ay * ay + az * az);
    float tt = fminf(d * INVSTEP, (float)(TBL - 2) + 0.999f);
    int id = (int)tt;
    int c = col[e];
    int pos = atomicAdd(&cursor[c], 1);
    unsigned mw = ((unsigned)row[e] << 16) | ((unsigned)id << 4) | (unsigned)(c & 15);
    metap[pos] = make_uint2(mw, __float_as_uint(tt - (float)id));
  }
}

// ================= filter table build (packed bf16 pairs, direct) ==========
__global__ __launch_bounds__(128) void k_tabbuild3(
    const float* __restrict__ Wf1, const float* __restrict__ bf1,
    const float* __restrict__ Wf2, const float* __restrict__ bf2,
    unsigned int* __restrict__ tabp) {
  const int bid = blockIdx.x;            // 0 .. NL*(TBL/8)-1
  const int l = bid / (TBL / 8);
  const int t0 = (bid - l * (TBL / 8)) * 8;
  const int c = threadIdx.x;
  __shared__ float g_s[9][NG];
  __shared__ float f1_s[9][NF];
  for (int i = c; i < 9 * NG; i += 128) {
    int kk = i / NG, g = i - kk * NG;
    int t = min(t0 + kk, TBL - 1);
    float d = (float)t * (1.0f / INVSTEP);
    float z = d - 0.2040816327f * (float)g;
    g_s[kk][g] = expf(-12.005f * z * z);
  }
  __syncthreads();
  const float* W1 = Wf1 + (size_t)l * NG * NF;
  float f1r[9];
#pragma unroll
  for (int kk = 0; kk < 9; ++kk) f1r[kk] = bf1[(size_t)l * NF + c];
  for (int g = 0; g < NG; ++g) {
    float w = W1[g * NF + c];
#pragma unroll
    for (int kk = 0; kk < 9; ++kk) f1r[kk] = fmaf(g_s[kk][g], w, f1r[kk]);
  }
#pragma unroll
  for (int kk = 0; kk < 9; ++kk) f1_s[kk][c] = fmaxf(f1r[kk], 0.f);
  __syncthreads();
  const float* W2 = Wf2 + (size_t)l * NF * NF;
  float outr[9];
#pragma unroll
  for (int kk = 0; kk < 9; ++kk) outr[kk] = bf2[(size_t)l * NF + c];
  for (int k = 0; k < NF; ++k) {
    float w = W2[k * NF + c];
#pragma unroll
    for (int kk = 0; kk < 9; ++kk) outr[kk] = fmaf(f1_s[kk][k], w, outr[kk]);
  }
#pragma unroll
  for (int kk = 0; kk < 8; ++kk)
    tabp[((size_t)l * TBL + t0 + kk) * NF + c] = pack_bf2(outr[kk], outr[kk + 1]);
}

// ================= merged weight prep: node MLP + enc2/shift ===============
__global__ __launch_bounds__(256) void k_prepall(
    const float* __restrict__ Wd1, const float* __restrict__ Wd2,
    const float* __restrict__ We2, const float* __restrict__ Ws1,
    const float* __restrict__ Ws2,
    bf16_t* __restrict__ Wd1Thi, bf16_t* __restrict__ Wd1Tlo,
    bf16_t* __restrict__ Wd2Thi, bf16_t* __restrict__ Wd2Tlo,
    bf16_t* __restrict__ We2Thi, bf16_t* __restrict__ We2Tlo,
    bf16_t* __restrict__ Ws1Thi, bf16_t* __restrict__ Ws1Tlo,
    bf16_t* __restrict__ Ws2Thi, bf16_t* __restrict__ Ws2Tlo) {
  const int S1 = NL * 128 * 128;     // per Wd
  const int S0 = 128 * 128;          // We2
  const int SA = 64 * 256;           // Ws1
  const int SB = 64 * 64;            // Ws2
  int idx = blockIdx.x * 256 + threadIdx.x;
  if (idx < 2 * S1) {
    int which = idx / S1;
    int jj = idx - which * S1;
    int l = jj / (128 * 128);
    int r = jj - l * (128 * 128);
    int c = r >> 7, k = r & 127;
    const float* W = (which == 0) ? Wd1 : Wd2;
    float v = W[(size_t)l * 128 * 128 + (size_t)k * 128 + c];
    bf16_t hv = (bf16_t)v;
    bf16_t lv = (bf16_t)(v - (float)hv);
    if (which == 0) { Wd1Thi[jj] = hv; Wd1Tlo[jj] = lv; }
    else            { Wd2Thi[jj] = hv; Wd2Tlo[jj] = lv; }
  } else {
    int j = idx - 2 * S1;
    if (j < S0) {
      int c = j >> 7, k = j & 127;
      float v = We2[k * 128 + c];
      bf16_t hv = (bf16_t)v;
      We2Thi[j] = hv; We2Tlo[j] = (bf16_t)(v - (float)hv);
    } else if (j < S0 + SA) {
      int jj = j - S0;
      int c = jj >> 8, k = jj & 255;
      float v = Ws1[k * 64 + c];
      bf16_t hv = (bf16_t)v;
      Ws1Thi[jj] = hv; Ws1Tlo[jj] = (bf16_t)(v - (float)hv);
    } else if (j < S0 + SA + SB) {
      int jj = j - S0 - SA;
      int c = jj >> 6, k = jj & 63;
      float v = Ws2[k * 64 + c];
      bf16_t hv = (bf16_t)v;
      Ws2Thi[jj] = hv; Ws2Tlo[jj] = (bf16_t)(v - (float)hv);
    }
  }
}

// ================= node encoder pass 1 =====================================
__global__ __launch_bounds__(256) void k_enc1(const float* __restrict__ x,
    const float* __restrict__ We1, const float* __restrict__ be1,
    float* __restrict__ t, float* __restrict__ stats) {
  int c = threadIdx.x & 127;
  int half = threadIdx.x >> 7;
  float b = be1[c];
  float psum = 0.f, psq = 0.f;
  for (int n = blockIdx.x * 2 + half; n < NN; n += gridDim.x * 2) {
    const float* xr = x + (size_t)n * XD;
    float v = b;
#pragma unroll
    for (int k = 0; k < XD; ++k) v = fmaf(xr[k], We1[k * HID + c], v);
    t[(size_t)n * HID + c] = v;
    psum += v; psq += v * v;
  }
  __shared__ float s0[256], s1[256];
  s0[threadIdx.x] = psum; s1[threadIdx.x] = psq;
  __syncthreads();
  if (threadIdx.x < 128) {
    atomicAdd(&stats[threadIdx.x], s0[threadIdx.x] + s0[threadIdx.x + 128]);
    atomicAdd(&stats[128 + threadIdx.x], s1[threadIdx.x] + s1[threadIdx.x + 128]);
  }
}

__global__ __launch_bounds__(128) void k_bn_fin(const float* __restrict__ gamma,
    const float* __restrict__ beta, float* __restrict__ stats, int C, float invn) {
  int c = threadIdx.x;
  if (c < C) {
    float mean = stats[c] * invn;
    float var = stats[128 + c] * invn - mean * mean;
    float a = gamma[c] * rsqrtf(var + EPSF);
    stats[256 + c] = a;
    stats[384 + c] = beta[c] - mean * a;
  }
}

// ================= node encoder pass 2 (MFMA) ==============================
__global__ __launch_bounds__(256) void k_enc2m(const float* __restrict__ t,
    const float* __restrict__ stats,
    const bf16_t* __restrict__ We2Thi, const bf16_t* __restrict__ We2Tlo,
    const float* __restrict__ be2, float* __restrict__ h,
    unsigned int* __restrict__ hbf) {
  __shared__ __align__(16) bf16_t rhi[16][136];
  __shared__ __align__(16) bf16_t rlo[16][136];
  const int tid = threadIdx.x, lane = tid & 63, w = tid >> 6;
  const int lm = lane & 15, lk = lane >> 4;
  const int nb = blockIdx.x * 16;
  for (int i = tid; i < 16 * 128; i += 256) {
    int r = i >> 7, k = i & 127;
    float v = fmaxf(fmaf(t[(size_t)(nb + r) * HID + k], stats[256 + k], stats[384 + k]), 0.f);
    bf16_t hv = (bf16_t)v;
    rhi[r][k] = hv; rlo[r][k] = (bf16_t)(v - (float)hv);
  }
  __syncthreads();
  const int colb = w * 32, k0base = lk * 8;
  f32x4 acc[2];
  acc[0] = (f32x4){0.f, 0.f, 0.f, 0.f};
  acc[1] = (f32x4){0.f, 0.f, 0.f, 0.f};
#pragma unroll
  for (int s = 0; s < 4; ++s) {
    int k0 = s * 32 + k0base;
    bf16x8 Ahi = *(const bf16x8*)&rhi[lm][k0];
    bf16x8 Alo = *(const bf16x8*)&rlo[lm][k0];
#pragma unroll
    for (int cf = 0; cf < 2; ++cf) {
      int cc = colb + cf * 16 + lm;
      bf16x8 Bh = *(const bf16x8*)(We2Thi + (size_t)cc * 128 + k0);
      bf16x8 Bl = *(const bf16x8*)(We2Tlo + (size_t)cc * 128 + k0);
      acc[cf] = __builtin_amdgcn_mfma_f32_16x16x32_bf16(Ahi, Bh, acc[cf], 0, 0, 0);
      acc[cf] = __builtin_amdgcn_mfma_f32_16x16x32_bf16(Ahi, Bl, acc[cf], 0, 0, 0);
      acc[cf] = __builtin_amdgcn_mfma_f32_16x16x32_bf16(Alo, Bh, acc[cf], 0, 0, 0);
    }
  }
#pragma unroll
  for (int cf = 0; cf < 2; ++cf) {
    int cc = colb + cf * 16 + lm;
    float bias = be2[cc];
#pragma unroll
    for (int j = 0; j < 4; ++j) {
      int r = nb + lk * 4 + j;
      float val = acc[cf][j] + bias;
      h[(size_t)r * HID + cc] = val;
      float o = __shfl_xor(val, 1);
      if ((lm & 1) == 0) hbf[(size_t)r * 64 + (cc >> 1)] = pack_bf2(val, o);
    }
  }
}

// ================= gaussian smearing (ea output, float2 stores) ============
__global__ __launch_bounds__(256) void k_smear(const float* __restrict__ eattr,
    float* __restrict__ ea) {
  int idx = blockIdx.x * 256 + threadIdx.x;  // over NE*25
  if (idx >= NE * (NG / 2)) return;
  int e = idx / (NG / 2);
  int g0 = (idx - e * (NG / 2)) * 2;
  float ax = eattr[(size_t)e * 3], ay = eattr[(size_t)e * 3 + 1], az = eattr[(size_t)e * 3 + 2];
  float d = sqrtf(ax * ax + ay * ay + az * az);
  float z0 = d - 0.2040816327f * (float)g0;
  float z1 = d - 0.2040816327f * (float)(g0 + 1);
  float2 v = make_float2(__expf(-12.005f * z0 * z0), __expf(-12.005f * z1 * z1));
  *(float2*)(ea + (size_t)e * NG + g0) = v;
}

// ================= fused layer kernel ======================================
__global__ __launch_bounds__(256) void k_layer(
    const uint2* __restrict__ metap, const int* __restrict__ rowptr,
    const float* __restrict__ hin, const unsigned int* __restrict__ hbf,
    const unsigned int* __restrict__ tabp,
    const bf16_t* __restrict__ Wd1Thi, const bf16_t* __restrict__ Wd1Tlo,
    const bf16_t* __restrict__ Wd2Thi, const bf16_t* __restrict__ Wd2Tlo,
    const float* __restrict__ bd1, const float* __restrict__ bd2,
    float* __restrict__ hout, unsigned int* __restrict__ hbfo) {
  __shared__ __align__(16) char up[8704];          // agg_s  ∪  (t1hi,t1lo)
  float (*agg_s)[HID] = (float(*)[HID])up;
  bf16_t (*t1hi)[136] = (bf16_t(*)[136])up;
  bf16_t (*t1lo)[136] = (bf16_t(*)[136])(up + 4352);
  __shared__ __align__(16) bf16_t ahi_s[16][136];
  __shared__ __align__(16) bf16_t alo_s[16][136];

  const int tid = threadIdx.x;
  const int lane = tid & 63;
  const int w = tid >> 6;
  const int half = lane >> 5;          // which edge of the pair
  const int c0 = (lane & 31) * 4;      // 4 owned cols
  const int hoff = c0 >> 1;            // u32 index into hbf row
  const int nb = blockIdx.x * 16;
  const int eS = rowptr[nb], eE = rowptr[nb + 16];

  for (int i = tid; i < 16 * HID; i += 256) ((float*)agg_s)[i] = 0.f;
  __syncthreads();

  // ---------------- phase 1: edges (2-deep pipelined pairs) ----------------
  {
    const int Q = (eE - eS + 3) >> 2;
    int e = eS + w * Q;
    const int wE = min(e + Q, eE);

    float a0 = 0.f, a1 = 0.f, a2 = 0.f, a3 = 0.f;
    int cur = -1;

    auto flush = [&]() {
      if (cur >= 0) {
        atomicAdd(&agg_s[cur][c0], a0);
        atomicAdd(&agg_s[cur][c0 + 1], a1);
        atomicAdd(&agg_s[cur][c0 + 2], a2);
        atomicAdd(&agg_s[cur][c0 + 3], a3);
      }
    };
    auto pbody = [&](const uint2& m, const uint2& hv, const uint4& tv) {
      float fr = __uint_as_float(m.y);
      int dst = m.x & 0xF;
      float m0 = blerp(tv.x, fr) * bflo(hv.x);
      float m1 = blerp(tv.y, fr) * bfhi(hv.x);
      float m2 = blerp(tv.z, fr) * bflo(hv.y);
      float m3 = blerp(tv.w, fr) * bfhi(hv.y);
      if (dst != cur) {
        flush();
        cur = dst; a0 = m0; a1 = m1; a2 = m2; a3 = m3;
      } else {
        a0 += m0; a1 += m1; a2 += m2; a3 += m3;
      }
    };
    auto loadd = [&](const uint2& m, uint2& hv, uint4& tv) {
      hv = *(const uint2*)(hbf + (size_t)(m.x >> 16) * 64 + hoff);
      tv = *(const uint4*)(tabp + (size_t)((m.x >> 4) & 0xFFFu) * HID + c0);
    };

    if (wE - e >= 8) {
      uint2 m0a = metap[e + half], m0b = metap[e + 2 + half];
      uint2 hv0a, hv0b; uint4 tv0a, tv0b;
      loadd(m0a, hv0a, tv0a); loadd(m0b, hv0b, tv0b);
      int ep = e + 4;
      uint2 m1a = metap[ep + half], m1b = metap[ep + 2 + half];
      while (true) {
        const bool more = (ep + 8 <= wE);
        uint2 hv1a, hv1b; uint4 tv1a, tv1b;
        loadd(m1a, hv1a, tv1a); loadd(m1b, hv1b, tv1b);
        uint2 m2a, m2b;
        if (more) { m2a = metap[ep + 4 + half]; m2b = metap[ep + 6 + half]; }
        pbody(m0a, hv0a, tv0a);
        pbody(m0b, hv0b, tv0b);
        if (!more) {
          pbody(m1a, hv1a, tv1a);
          pbody(m1b, hv1b, tv1b);
          ep += 4;
          break;
        }
        m0a = m1a; m0b = m1b;
        hv0a = hv1a; hv0b = hv1b; tv0a = tv1a; tv0b = tv1b;
        m1a = m2a; m1b = m2b;
        ep += 4;
      }
      e = ep;
    }
    for (; e < wE; e += 2) {
      int le = e + half;
      bool valid = le < wE;
      uint2 m = metap[valid ? le : (wE - 1)];
      uint2 hv; uint4 tv;
      loadd(m, hv, tv);
      if (valid) pbody(m, hv, tv);
    }
    flush();
  }
  __syncthreads();

  // ---------------- phase 2: node MLP on agg_s ----------------
  for (int i = tid; i < 16 * 128; i += 256) {
    int r = i >> 7, k = i & 127;
    float v = agg_s[r][k];
    bf16_t hv = (bf16_t)v;
    ahi_s[r][k] = hv;
    alo_s[r][k] = (bf16_t)(v - (float)hv);
  }
  __syncthreads();  // agg_s dead; t1hi/t1lo may now overwrite it

  const int lm = lane & 15;
  const int lk = lane >> 4;
  const int colb = w * 32;
  const int k0base = lk * 8;

  // GEMM1: t1 = relu(agg @ Wd1 + bd1)
  f32x4 acc1g[2];
  acc1g[0] = (f32x4){0.f, 0.f, 0.f, 0.f};
  acc1g[1] = (f32x4){0.f, 0.f, 0.f, 0.f};
#pragma unroll
  for (int s = 0; s < 4; ++s) {
    int k0 = s * 32 + k0base;
    bf16x8 Ahi = *(const bf16x8*)&ahi_s[lm][k0];
    bf16x8 Alo = *(const bf16x8*)&alo_s[lm][k0];
#pragma unroll
    for (int cf = 0; cf < 2; ++cf) {
      int cc = colb + cf * 16 + lm;
      bf16x8 Bh = *(const bf16x8*)(Wd1Thi + (size_t)cc * 128 + k0);
      bf16x8 Bl = *(const bf16x8*)(Wd1Tlo + (size_t)cc * 128 + k0);
      acc1g[cf] = __builtin_amdgcn_mfma_f32_16x16x32_bf16(Ahi, Bh, acc1g[cf], 0, 0, 0);
      acc1g[cf] = __builtin_amdgcn_mfma_f32_16x16x32_bf16(Ahi, Bl, acc1g[cf], 0, 0, 0);
      acc1g[cf] = __builtin_amdgcn_mfma_f32_16x16x32_bf16(Alo, Bh, acc1g[cf], 0, 0, 0);
    }
  }
#pragma unroll
  for (int cf = 0; cf < 2; ++cf) {
    int cc = colb + cf * 16 + lm;
    float bias1 = bd1[cc];
#pragma unroll
    for (int j = 0; j < 4; ++j) {
      int r = lk * 4 + j;
      float v = fmaxf(acc1g[cf][j] + bias1, 0.f);
      bf16_t hv = (bf16_t)v;
      t1hi[r][cc] = hv;
      t1lo[r][cc] = (bf16_t)(v - (float)hv);
    }
  }
  __syncthreads();

  // GEMM2: out = t1 @ Wd2 + bd2;  hout = hin + out (+ packed bf16 copy)
  f32x4 acc2g[2];
  acc2g[0] = (f32x4){0.f, 0.f, 0.f, 0.f};
  acc2g[1] = (f32x4){0.f, 0.f, 0.f, 0.f};
#pragma unroll
  for (int s = 0; s < 4; ++s) {
    int k0 = s * 32 + k0base;
    bf16x8 Ahi = *(const bf16x8*)&t1hi[lm][k0];
    bf16x8 Alo = *(const bf16x8*)&t1lo[lm][k0];
#pragma unroll
    for (int cf = 0; cf < 2; ++cf) {
      int cc = colb + cf * 16 + lm;
      bf16x8 Bh = *(const bf16x8*)(Wd2Thi + (size_t)cc * 128 + k0);
      bf16x8 Bl = *(const bf16x8*)(Wd2Tlo + (size_t)cc * 128 + k0);
      acc2g[cf] = __builtin_amdgcn_mfma_f32_16x16x32_bf16(Ahi, Bh, acc2g[cf], 0, 0, 0);
      acc2g[cf] = __builtin_amdgcn_mfma_f32_16x16x32_bf16(Ahi, Bl, acc2g[cf], 0, 0, 0);
      acc2g[cf] = __builtin_amdgcn_mfma_f32_16x16x32_bf16(Alo, Bh, acc2g[cf], 0, 0, 0);
    }
  }
#pragma unroll
  for (int cf = 0; cf < 2; ++cf) {
    int cc = colb + cf * 16 + lm;
    float bias2 = bd2[cc];
#pragma unroll
    for (int j = 0; j < 4; ++j) {
      int r = nb + lk * 4 + j;
      float val = hin[(size_t)r * HID + cc] + acc2g[cf][j] + bias2;
      hout[(size_t)r * HID + cc] = val;
      float o = __shfl_xor(val, 1);
      if ((lm & 1) == 0) hbfo[(size_t)r * 64 + (cc >> 1)] = pack_bf2(val, o);
    }
  }
}

// ================= global MLP ==============================================
__global__ __launch_bounds__(128) void k_global(const float* __restrict__ u,
    const float* __restrict__ Wg1, const float* __restrict__ bg1,
    const float* __restrict__ gg1, const float* __restrict__ btg1,
    const float* __restrict__ Wg2, const float* __restrict__ bg2,
    float* __restrict__ u_p) {
  __shared__ float t_s[NGR][HID];
  int c = threadIdx.x;
  for (int g = 0; g < NGR; ++g) {
    float v = bg1[c];
#pragma unroll
    for (int k = 0; k < GD; ++k) v = fmaf(u[(size_t)g * GD + k], Wg1[k * HID + c], v);
    t_s[g][c] = v;
  }
  float sum = 0.f, sq = 0.f;
  for (int g = 0; g < NGR; ++g) { float v = t_s[g][c]; sum += v; sq += v * v; }
  float mean = sum * (1.f / NGR);
  float var = sq * (1.f / NGR) - mean * mean;
  float a = gg1[c] * rsqrtf(var + EPSF);
  float b = btg1[c] - mean * a;
  for (int g = 0; g < NGR; ++g) t_s[g][c] = fmaxf(fmaf(t_s[g][c], a, b), 0.f);
  __syncthreads();
  for (int g = 0; g < NGR; ++g) {
    float acc = bg2[c];
#pragma unroll 8
    for (int k = 0; k < HID; ++k) acc = fmaf(t_s[g][k], Wg2[k * HID + c], acc);
    u_p[(size_t)g * HID + c] = acc;
  }
}

// ================= shift head pass 1 (MFMA, K=256) =========================
__global__ __launch_bounds__(256) void k_shift1m(
    const float* __restrict__ h, const float* __restrict__ u_p,
    const int* __restrict__ batch,
    const bf16_t* __restrict__ Ws1Thi, const bf16_t* __restrict__ Ws1Tlo,
    const float* __restrict__ bs1, float* __restrict__ t1,
    float* __restrict__ stats) {
  __shared__ __align__(16) bf16_t shi[16][264];
  __shared__ __align__(16) bf16_t slo[16][264];
  const int tid = threadIdx.x, lane = tid & 63, w = tid >> 6;
  const int lm = lane & 15, lk = lane >> 4;
  const int nb = blockIdx.x * 16;
  for (int i = tid; i < 16 * 128; i += 256) {
    int ln = i >> 7, k = i & 127;
    float v1 = h[(size_t)(nb + ln) * HID + k];
    float v2 = u_p[(size_t)batch[nb + ln] * HID + k];
    bf16_t h1 = (bf16_t)v1;
    shi[ln][k] = h1; slo[ln][k] = (bf16_t)(v1 - (float)h1);
    bf16_t h2 = (bf16_t)v2;
    shi[ln][128 + k] = h2; slo[ln][128 + k] = (bf16_t)(v2 - (float)h2);
  }
  __syncthreads();
  const int cc = w * 16 + lm;
  f32x4 acc = (f32x4){0.f, 0.f, 0.f, 0.f};
#pragma unroll
  for (int s = 0; s < 8; ++s) {
    int k0 = s * 32 + lk * 8;
    bf16x8 Ahi = *(const bf16x8*)&shi[lm][k0];
    bf16x8 Alo = *(const bf16x8*)&slo[lm][k0];
    bf16x8 Bh = *(const bf16x8*)(Ws1Thi + (size_t)cc * 256 + k0);
    bf16x8 Bl = *(const bf16x8*)(Ws1Tlo + (size_t)cc * 256 + k0);
    acc = __builtin_amdgcn_mfma_f32_16x16x32_bf16(Ahi, Bh, acc, 0, 0, 0);
    acc = __builtin_amdgcn_mfma_f32_16x16x32_bf16(Ahi, Bl, acc, 0, 0, 0);
    acc = __builtin_amdgcn_mfma_f32_16x16x32_bf16(Alo, Bh, acc, 0, 0, 0);
  }
  float bias = bs1[cc];
  float psum = 0.f, psq = 0.f;
#pragma unroll
  for (int j = 0; j < 4; ++j) {
    float val = acc[j] + bias;
    t1[(size_t)(nb + lk * 4 + j) * SH + cc] = val;
    psum += val; psq += val * val;
  }
  psum += __shfl_xor(psum, 16); psum += __shfl_xor(psum, 32);
  psq  += __shfl_xor(psq, 16);  psq  += __shfl_xor(psq, 32);
  if (lk == 0) {
    atomicAdd(&stats[cc], psum);
    atomicAdd(&stats[128 + cc], psq);
  }
}

// ================= shift head pass 2 (MFMA, K=64) ==========================
__global__ __launch_bounds__(256) void k_shift2m(
    const float* __restrict__ t1, float* __restrict__ stats,
    const bf16_t* __restrict__ Ws2Thi, const bf16_t* __restrict__ Ws2Tlo,
    const float* __restrict__ bs2, float* __restrict__ t2) {
  __shared__ __align__(16) bf16_t rhi[16][72];
  __shared__ __align__(16) bf16_t rlo[16][72];
  const int tid = threadIdx.x, lane = tid & 63, w = tid >> 6;
  const int lm = lane & 15, lk = lane >> 4;
  const int nb = blockIdx.x * 16;
  for (int i = tid; i < 16 * 64; i += 256) {
    int ln = i >> 6, k = i & 63;
    float v = fmaxf(fmaf(t1[(size_t)(nb + ln) * SH + k], stats[256 + k], stats[384 + k]), 0.f);
    bf16_t hv = (bf16_t)v;
    rhi[ln][k] = hv; rlo[ln][k] = (bf16_t)(v - (float)hv);
  }
  __syncthreads();
  const int cc = w * 16 + lm;
  f32x4 acc = (f32x4){0.f, 0.f, 0.f, 0.f};
#pragma unroll
  for (int s = 0; s < 2; ++s) {
    int k0 = s * 32 + lk * 8;
    bf16x8 Ahi = *(const bf16x8*)&rhi[lm][k0];
    bf16x8 Alo = *(const bf16x8*)&rlo[lm][k0];
    bf16x8 Bh = *(const bf16x8*)(Ws2Thi + (size_t)cc * 64 + k0);
    bf16x8 Bl = *(const bf16x8*)(Ws2Tlo + (size_t)cc * 64 + k0);
    acc = __builtin_amdgcn_mfma_f32_16x16x32_bf16(Ahi, Bh, acc, 0, 0, 0);
    acc = __builtin_amdgcn_mfma_f32_16x16x32_bf16(Ahi, Bl, acc, 0, 0, 0);
    acc = __builtin_amdgcn_mfma_f32_16x16x32_bf16(Alo, Bh, acc, 0, 0, 0);
  }
  float bias = bs2[cc];
  float psum = 0.f, psq = 0.f;
#pragma unroll
  for (int j = 0; j < 4; ++j) {
    float val = acc[j] + bias;
    t2[(size_t)(nb + lk * 4 + j) * SH + cc] = val;
    psum += val; psq += val * val;
  }
  psum += __shfl_xor(psum, 16); psum += __shfl_xor(psum, 32);
  psq  += __shfl_xor(psq, 16);  psq  += __shfl_xor(psq, 32);
  if (lk == 0) {
    atomicAdd(&stats[cc], psum);
    atomicAdd(&stats[128 + cc], psq);
  }
}

__global__ __launch_bounds__(256) void k_shift3(
    const float* __restrict__ t2, const float* __restrict__ stats,
    const float* __restrict__ Ws3, const float* __restrict__ bs3,
    float* __restrict__ shifts) {
  int lane = threadIdx.x & 63;
  int n = blockIdx.x * 4 + (threadIdx.x >> 6);
  if (n >= NN) return;
  float a = stats[256 + lane], b = stats[384 + lane];
  float r = fmaxf(fmaf(t2[(size_t)n * SH + lane], a, b), 0.f);
  float v = r * Ws3[lane];
#pragma unroll
  for (int off = 32; off; off >>= 1) v += __shfl_down(v, off);
  if (lane == 0) shifts[n] = v + bs3[0];
}

extern "C" void kernel_launch(void* const* d_in, const int* in_sizes, int n_in,
                              void* d_out, int out_size, void* d_ws, size_t ws_size,
                              hipStream_t stream) {
  const float* x     = (const float*)d_in[0];
  const int*   ei    = (const int*)d_in[1];
  const float* eattr = (const float*)d_in[2];
  const int*   batch = (const int*)d_in[3];
  const float* u     = (const float*)d_in[4];
  const float* We1 = (const float*)d_in[5];  const float* be1 = (const float*)d_in[6];
  const float* ge1 = (const float*)d_in[7];  const float* bte1 = (const float*)d_in[8];
  const float* We2 = (const float*)d_in[9];  const float* be2 = (const float*)d_in[10];
  const float* Wf1 = (const float*)d_in[11]; const float* bf1 = (const float*)d_in[12];
  const float* Wf2 = (const float*)d_in[13]; const float* bf2 = (const float*)d_in[14];
  const float* Wd1 = (const float*)d_in[15]; const float* bd1 = (const float*)d_in[16];
  const float* Wd2 = (const float*)d_in[17]; const float* bd2 = (const float*)d_in[18];
  const float* Wg1 = (const float*)d_in[19]; const float* bg1 = (const float*)d_in[20];
  const float* gg1 = (const float*)d_in[21]; const float* btg1 = (const float*)d_in[22];
  const float* Wg2 = (const float*)d_in[23]; const float* bg2 = (const float*)d_in[24];
  const float* Ws1 = (const float*)d_in[25]; const float* bs1 = (const float*)d_in[26];
  const float* gs1 = (const float*)d_in[27]; const float* bts1 = (const float*)d_in[28];
  const float* Ws2 = (const float*)d_in[29]; const float* bs2 = (const float*)d_in[30];
  const float* gs2 = (const float*)d_in[31]; const float* bts2 = (const float*)d_in[32];
  const float* Ws3 = (const float*)d_in[33]; const float* bs3 = (const float*)d_in[34];

  float* out    = (float*)d_out;
  float* shifts = out;                    // [NN]
  float* h      = out + NN;               // [NN,HID]
  float* ea     = out + NN + NN * HID;    // [NE,NG]
  float* u_p    = out + NN + NN * HID + (size_t)NE * NG;  // [NGR,HID]

  // workspace layout
  char* wsb = (char*)d_ws;
  size_t off = 0;
  auto alloc = [&](size_t bytes) { void* p = wsb + off; off = (off + bytes + 255) & ~(size_t)255; return p; };
  float*  stats    = (float*)alloc(512 * sizeof(float));
  int*    hist     = (int*)alloc((size_t)NN * sizeof(int));
  int*    rowptr   = (int*)alloc((size_t)(NN + 1) * sizeof(int));
  uint2*  metap    = (uint2*)alloc((size_t)NE * sizeof(uint2));
  unsigned int* tabp = (unsigned int*)alloc((size_t)NL * TBL * HID * sizeof(unsigned int));
  bf16_t* Wd1Thi   = (bf16_t*)alloc((size_t)NL * 128 * 128 * sizeof(bf16_t));
  bf16_t* Wd1Tlo   = (bf16_t*)alloc((size_t)NL * 128 * 128 * sizeof(bf16_t));
  bf16_t* Wd2Thi   = (bf16_t*)alloc((size_t)NL * 128 * 128 * sizeof(bf16_t));
  bf16_t* Wd2Tlo   = (bf16_t*)alloc((size_t)NL * 128 * 128 * sizeof(bf16_t));
  bf16_t* We2Thi   = (bf16_t*)alloc((size_t)128 * 128 * sizeof(bf16_t));
  bf16_t* We2Tlo   = (bf16_t*)alloc((size_t)128 * 128 * sizeof(bf16_t));
  bf16_t* Ws1Thi   = (bf16_t*)alloc((size_t)64 * 256 * sizeof(bf16_t));
  bf16_t* Ws1Tlo   = (bf16_t*)alloc((size_t)64 * 256 * sizeof(bf16_t));
  bf16_t* Ws2Thi   = (bf16_t*)alloc((size_t)64 * 64 * sizeof(bf16_t));
  bf16_t* Ws2Tlo   = (bf16_t*)alloc((size_t)64 * 64 * sizeof(bf16_t));
  float*  hwork    = (float*)alloc((size_t)NN * HID * sizeof(float));
  unsigned int* hbfA = (unsigned int*)alloc((size_t)NN * 64 * sizeof(unsigned int));
  unsigned int* hbfB = (unsigned int*)alloc((size_t)NN * 64 * sizeof(unsigned int));
  float*  buf1     = (float*)alloc((size_t)NN * HID * sizeof(float));
  float* t1 = buf1;
  float* t2 = buf1 + (size_t)NN * SH;

  const int* row = ei;        // source j
  const int* col = ei + NE;   // target i

  // ---- CSR build + packed edge meta + table + merged weight prep
  hipMemsetAsync(hist, 0, (size_t)NN * sizeof(int), stream);
  k_hist<<<512, 256, 0, stream>>>(col, hist);
  k_scan<<<1, 1024, 0, stream>>>(hist, rowptr);
  k_scatter2<<<512, 256, 0, stream>>>(col, row, eattr, hist, metap);
  k_tabbuild3<<<NL * (TBL / 8), 128, 0, stream>>>(Wf1, bf1, Wf2, bf2, tabp);
  {
    const int total = 2 * NL * 128 * 128 + 128 * 128 + 64 * 256 + 64 * 64;
    k_prepall<<<(total + 255) / 256, 256, 0, stream>>>(
        Wd1, Wd2, We2, Ws1, Ws2,
        Wd1Thi, Wd1Tlo, Wd2Thi, Wd2Tlo,
        We2Thi, We2Tlo, Ws1Thi, Ws1Tlo, Ws2Thi, Ws2Tlo);
  }

  // ---- node encoder
  hipMemsetAsync(stats, 0, 256 * sizeof(float), stream);
  k_enc1<<<512, 256, 0, stream>>>(x, We1, be1, buf1, stats);
  k_bn_fin<<<1, 128, 0, stream>>>(ge1, bte1, stats, 128, 1.f / NN);
  k_enc2m<<<NN / 16, 256, 0, stream>>>(buf1, stats, We2Thi, We2Tlo, be2, h, hbfA);

  // ---- gaussian smearing (ea output)
  k_smear<<<(NE * (NG / 2) + 255) / 256, 256, 0, stream>>>(eattr, ea);

  // ---- interaction layers (fused edge+node, ping-pong h and hbf)
  for (int l = 0; l < NL; ++l) {
    const float* hi = (l & 1) ? hwork : h;
    float*       ho = (l & 1) ? h : hwork;
    const unsigned int* bi = (l & 1) ? hbfB : hbfA;
    unsigned int*       bo = (l & 1) ? hbfA : hbfB;
    k_layer<<<NN / 16, 256, 0, stream>>>(
        metap, rowptr, hi, bi, tabp + (size_t)l * TBL * HID,
        Wd1Thi + (size_t)l * 128 * 128, Wd1Tlo + (size_t)l * 128 * 128,
        Wd2Thi + (size_t)l * 128 * 128, Wd2Tlo + (size_t)l * 128 * 128,
        bd1 + (size_t)l * HID, bd2 + (size_t)l * HID, ho, bo);
  }
  // NL=6 (even) -> final h lands back in the output slot `h`

  // ---- global MLP
  k_global<<<1, 128, 0, stream>>>(u, Wg1, bg1, gg1, btg1, Wg2, bg2, u_p);

  // ---- shift head
  hipMemsetAsync(stats, 0, 256 * sizeof(float), stream);
  k_shift1m<<<NN / 16, 256, 0, stream>>>(h, u_p, batch, Ws1Thi, Ws1Tlo, bs1, t1, stats);
  k_bn_fin<<<1, 128, 0, stream>>>(gs1, bts1, stats, 64, 1.f / NN);
  hipMemsetAsync(stats, 0, 256 * sizeof(float), stream);
  k_shift2m<<<NN / 16, 256, 0, stream>>>(t1, stats, Ws2Thi, Ws2Tlo, bs2, t2);
  k_bn_fin<<<1, 128, 0, stream>>>(gs2, bts2, stats, 64, 1.f / NN);
  k_shift3<<<(NN + 3) / 4, 256, 0, stream>>>(t2, stats, Ws3, bs3, shifts);
}